// Round 5
// baseline (197.826 us; speedup 1.0000x reference)
//
#include <hip/hip_runtime.h>

// YOLOv1 loss on MI355X — max-ILP pure-streaming version (probe + candidate).
//
// Each thread processes 4 CONSECUTIVE cells = 192 contiguous bytes per input
// (exactly 3 aligned 64B lines). No LDS, no barriers, no cross-lane data
// movement, no loop-carried prefetch state (nothing to spill). 24 independent
// global_load_dwordx4 per thread for maximum memory-level parallelism.
//
// Inputs (setup_inputs order):
//   d_in[0] bounding_boxes: (16384,12,12,12) f32   — [x1,y1,w1,h1,c1, x2,y2,w2,h2,c2, cls0,cls1]
//   d_in[1] ground_truth:   (16384,12,12,1,12) f32 — [x,y,w,h,conf, l,u,r,d, obj, cls0,cls1]
//   d_in[2] grid_size: int scalar (8)
//   d_in[3] img_size:  int scalar (96)
// Output: 6 f32: loss, l_coord, loss_confidence, l_cls, iou_sum, object_num

#define S_DIM 12
#define CELLS_PER_IMG (S_DIM * S_DIM)        // 144
#define NCELLS (16384 * CELLS_PER_IMG)       // 2,359,296
#define CPT 4                                // cells per thread
#define GRID_BLKS (NCELLS / (256 * CPT))     // 2304 blocks exact (9 per CU)
#define L_COORD_C 5.0f
#define L_NOOBJ_C 0.5f

__device__ __forceinline__ float sq_sqrt(float t) {
    return sqrtf(fmaxf(t, 0.0f) + 1e-08f);
}

__global__ __launch_bounds__(256) void yolo_loss_main(
    const float4* __restrict__ bb4,
    const float4* __restrict__ gt4,
    const int* __restrict__ gs_p,
    const int* __restrict__ im_p,
    float* __restrict__ out)
{
    const float gs = (float)(*gs_p);
    const float im = (float)(*im_p);
    const float im1 = im - 1.0f;

    float s_conf = 0.0f, s_coord = 0.0f, s_cls = 0.0f, s_iou = 0.0f, s_obj = 0.0f;

    const int n0 = (blockIdx.x * 256 + threadIdx.x) * CPT;  // first cell of this thread
    const float4* pb = bb4 + (size_t)n0 * 3;                // 192 B contiguous per input
    const float4* pg = gt4 + (size_t)n0 * 3;

    int rem = n0 % CELLS_PER_IMG;   // cell position within image (cells are consecutive)

    #pragma unroll
    for (int c = 0; c < CPT; ++c) {
        const float4 b0 = pb[3 * c];       // x1,y1,w1,h1
        const float4 b1 = pb[3 * c + 1];   // c1,x2,y2,w2
        const float4 b2 = pb[3 * c + 2];   // h2,c2,cls0,cls1
        const float4 g0 = pg[3 * c];       // x,y,w,h
        const float4 g1 = pg[3 * c + 1];   // conf,l,u,r
        const float4 g2 = pg[3 * c + 2];   // d,obj,cls0,cls1

        const float c1 = b1.x;
        const float c2 = b2.y;
        const bool sel2 = c1 < c2;

        const float p0 = sel2 ? b1.y : b0.x;
        const float p1 = sel2 ? b1.z : b0.y;
        const float p2 = sel2 ? b1.w : b0.z;
        const float p3 = sel2 ? b2.x : b0.w;
        const float p4 = sel2 ? c2   : c1;    // sel_conf
        const float other = sel2 ? c1 : c2;   // other_conf

        const bool obj = (g2.y != 0.0f);
        const float objf = obj ? 1.0f : 0.0f;

        // confidence losses
        float conf_c = L_NOOBJ_C * other * other;
        const float dconf = g1.x - p4;
        conf_c += obj ? (dconf * dconf) : (L_NOOBJ_C * p4 * p4);
        s_conf += conf_c;

        // coord loss
        const float dx = g0.x - p0;
        const float dy = g0.y - p1;
        const float dw = sq_sqrt(g0.z) - sq_sqrt(p2);
        const float dh = sq_sqrt(g0.w) - sq_sqrt(p3);
        s_coord += objf * (L_COORD_C * (dx*dx + dy*dy + dw*dw + dh*dh));

        // class loss
        const float dc0 = g2.z - b2.z;
        const float dc1 = g2.w - b2.w;
        s_cls += objf * (dc0*dc0 + dc1*dc1);

        // IoU
        const int gi = rem / S_DIM;
        const int gj = rem % S_DIM;
        const float px = truncf((float)gj * gs + p0 * gs);
        const float py = truncf((float)gi * gs + p1 * gs);
        const float pw = truncf(p2 * im);
        const float ph = truncf(p3 * im);
        const float pl = fmaxf(0.0f, px - pw * 0.5f);
        const float pu = fmaxf(0.0f, py - ph * 0.5f);
        const float pr = fminf(im1, px + pw * 0.5f);
        const float pd = fminf(im1, py + ph * 0.5f);
        const float pA = (pr - pl) * (pd - pu);
        const float gl = g1.y, gu = g1.z, gr = g1.w, gd = g2.x;
        const float gA = (gr - gl) * (gd - gu);
        const float lx = fmaxf(pl, gl);
        const float rx = fminf(pr, gr);
        const float uy = fmaxf(pu, gu);
        const float dy2 = fminf(pd, gd);
        const float inter = (rx - lx) * (dy2 - uy);
        const float iou = ((rx < lx) || (dy2 < uy)) ? 0.0f : inter / (pA + gA - inter);
        s_iou += objf * iou;

        s_obj += objf;

        // consecutive cell -> rem+1 (wrap at 144)
        rem = (rem + 1 == CELLS_PER_IMG) ? 0 : rem + 1;
    }

    // wave reduction
    #pragma unroll
    for (int off = 32; off > 0; off >>= 1) {
        s_conf  += __shfl_down(s_conf,  off);
        s_coord += __shfl_down(s_coord, off);
        s_cls   += __shfl_down(s_cls,   off);
        s_iou   += __shfl_down(s_iou,   off);
        s_obj   += __shfl_down(s_obj,   off);
    }

    __shared__ float red[4][5];
    const int w = threadIdx.x >> 6;
    const int l = threadIdx.x & 63;
    if (l == 0) {
        red[w][0] = s_conf;
        red[w][1] = s_coord;
        red[w][2] = s_cls;
        red[w][3] = s_iou;
        red[w][4] = s_obj;
    }
    __syncthreads();
    if (threadIdx.x == 0) {
        float t0 = 0, t1 = 0, t2 = 0, t3 = 0, t4 = 0;
        #pragma unroll
        for (int v = 0; v < 4; ++v) {
            t0 += red[v][0]; t1 += red[v][1]; t2 += red[v][2];
            t3 += red[v][3]; t4 += red[v][4];
        }
        atomicAdd(&out[2], t0);  // loss_confidence
        atomicAdd(&out[1], t1);  // l_coord
        atomicAdd(&out[3], t2);  // l_cls
        atomicAdd(&out[4], t3);  // iou_sum
        atomicAdd(&out[5], t4);  // object_num
    }
}

__global__ void yolo_loss_finalize(float* __restrict__ out) {
    out[0] = out[1] + out[2] + out[3];
}

extern "C" void kernel_launch(void* const* d_in, const int* in_sizes, int n_in,
                              void* d_out, int out_size, void* d_ws, size_t ws_size,
                              hipStream_t stream) {
    const float4* bb4 = (const float4*)d_in[0];
    const float4* gt4 = (const float4*)d_in[1];
    const int* gs_p = (const int*)d_in[2];
    const int* im_p = (const int*)d_in[3];
    float* out = (float*)d_out;

    hipMemsetAsync(d_out, 0, 6 * sizeof(float), stream);

    yolo_loss_main<<<GRID_BLKS, 256, 0, stream>>>(bb4, gt4, gs_p, im_p, out);
    yolo_loss_finalize<<<1, 1, 0, stream>>>(out);
}

// Round 6
// 46.012 us; speedup vs baseline: 4.2994x; 4.2994x over previous
//
#include <hip/hip_runtime.h>

// YOLOv1 loss on MI355X — R2 block-LDS staging + SPREAD atomic accumulation.
//
// Key change vs R2 (127 us): all blocks previously atomicAdd'ed 5 values into
// ONE 64-B line of d_out; fitted cost ~17 ns per same-line atomic explains the
// 126-198 us plateau across all prior structures. Now block b accumulates into
// d_ws row (b & 63), 64 rows x 64 B (4 KB total, zeroed by memset each launch),
// reducing same-line atomics from 7680 to <=600 per line. A 64-lane finalize
// kernel sums the rows and writes the 6 outputs.
//
// Inputs (setup_inputs order):
//   d_in[0] bounding_boxes: (16384,12,12,12) f32   — [x1,y1,w1,h1,c1, x2,y2,w2,h2,c2, cls0,cls1]
//   d_in[1] ground_truth:   (16384,12,12,1,12) f32 — [x,y,w,h,conf, l,u,r,d, obj, cls0,cls1]
//   d_in[2] grid_size: int scalar (8)
//   d_in[3] img_size:  int scalar (96)
// Output: 6 f32: loss, l_coord, loss_confidence, l_cls, iou_sum, object_num

#define S_DIM 12
#define CELLS_PER_IMG (S_DIM * S_DIM)      // 144
#define NCELLS (16384 * CELLS_PER_IMG)     // 2,359,296
#define TILE 256                            // cells per block-iteration
#define F4_PER_TILE (TILE * 3)              // 768 float4 per input array
#define NTILES (NCELLS / TILE)              // 9216 (exact)
#define GRID_BLKS 1536                      // 6 tiles/block exact
#define NROWS 64                            // accumulator rows (64 B apart)
#define ROWF 16                             // floats per row (64 B)
#define L_COORD_C 5.0f
#define L_NOOBJ_C 0.5f

__device__ __forceinline__ float sq_sqrt(float t) {
    return sqrtf(fmaxf(t, 0.0f) + 1e-08f);
}

__global__ __launch_bounds__(256, 6) void yolo_loss_main(
    const float4* __restrict__ bb4,
    const float4* __restrict__ gt4,
    const int* __restrict__ gs_p,
    const int* __restrict__ im_p,
    float* __restrict__ ws)
{
    __shared__ float4 sb[F4_PER_TILE];   // 12 KB
    __shared__ float4 sg[F4_PER_TILE];   // 12 KB
    __shared__ float red[4][5];

    const float gs = (float)(*gs_p);
    const float im = (float)(*im_p);
    const float im1 = im - 1.0f;

    float s_conf = 0.0f, s_coord = 0.0f, s_cls = 0.0f, s_iou = 0.0f, s_obj = 0.0f;

    const int t = threadIdx.x;

    // prefetch tile 0 (lane-contiguous float4: 1 KB per wave-instruction)
    int tile = blockIdx.x;
    float4 rb0, rb1, rb2, rg0, rg1, rg2;
    {
        const size_t tb = (size_t)tile * F4_PER_TILE;
        rb0 = bb4[tb + t]; rb1 = bb4[tb + 256 + t]; rb2 = bb4[tb + 512 + t];
        rg0 = gt4[tb + t]; rg1 = gt4[tb + 256 + t]; rg2 = gt4[tb + 512 + t];
    }

    while (tile < NTILES) {
        __syncthreads();   // prior iteration's LDS reads complete before overwrite
        sb[t]       = rb0;
        sb[256 + t] = rb1;
        sb[512 + t] = rb2;
        sg[t]       = rg0;
        sg[256 + t] = rg1;
        sg[512 + t] = rg2;
        __syncthreads();

        const int next = tile + GRID_BLKS;
        if (next < NTILES) {   // issue next tile's loads; latency hides under compute
            const size_t tb = (size_t)next * F4_PER_TILE;
            rb0 = bb4[tb + t]; rb1 = bb4[tb + 256 + t]; rb2 = bb4[tb + 512 + t];
            rg0 = gt4[tb + t]; rg1 = gt4[tb + 256 + t]; rg2 = gt4[tb + 512 + t];
        }

        // this thread's cell: stride-3 float4 LDS reads (<=2-way conflict, free)
        const float4 b0 = sb[3 * t];       // x1,y1,w1,h1
        const float4 b1 = sb[3 * t + 1];   // c1,x2,y2,w2
        const float4 b2 = sb[3 * t + 2];   // h2,c2,cls0,cls1
        const float4 g0 = sg[3 * t];       // x,y,w,h
        const float4 g1 = sg[3 * t + 1];   // conf,l,u,r
        const float4 g2 = sg[3 * t + 2];   // d,obj,cls0,cls1

        const float c1 = b1.x;
        const float c2 = b2.y;
        const bool sel2 = c1 < c2;

        const float p0 = sel2 ? b1.y : b0.x;
        const float p1 = sel2 ? b1.z : b0.y;
        const float p2 = sel2 ? b1.w : b0.z;
        const float p3 = sel2 ? b2.x : b0.w;
        const float p4 = sel2 ? c2   : c1;    // sel_conf
        const float other = sel2 ? c1 : c2;   // other_conf

        const bool obj = (g2.y != 0.0f);
        const float objf = obj ? 1.0f : 0.0f;

        // confidence losses
        float conf_c = L_NOOBJ_C * other * other;
        const float dconf = g1.x - p4;
        conf_c += obj ? (dconf * dconf) : (L_NOOBJ_C * p4 * p4);
        s_conf += conf_c;

        // coord loss
        const float dx = g0.x - p0;
        const float dy = g0.y - p1;
        const float dw = sq_sqrt(g0.z) - sq_sqrt(p2);
        const float dh = sq_sqrt(g0.w) - sq_sqrt(p3);
        s_coord += objf * (L_COORD_C * (dx*dx + dy*dy + dw*dw + dh*dh));

        // class loss
        const float dc0 = g2.z - b2.z;
        const float dc1 = g2.w - b2.w;
        s_cls += objf * (dc0*dc0 + dc1*dc1);

        // IoU
        const int n = tile * TILE + t;
        const int rem = n % CELLS_PER_IMG;
        const int gi = rem / S_DIM;
        const int gj = rem % S_DIM;
        const float px = truncf((float)gj * gs + p0 * gs);
        const float py = truncf((float)gi * gs + p1 * gs);
        const float pw = truncf(p2 * im);
        const float ph = truncf(p3 * im);
        const float pl = fmaxf(0.0f, px - pw * 0.5f);
        const float pu = fmaxf(0.0f, py - ph * 0.5f);
        const float pr = fminf(im1, px + pw * 0.5f);
        const float pd = fminf(im1, py + ph * 0.5f);
        const float pA = (pr - pl) * (pd - pu);
        const float gl = g1.y, gu = g1.z, gr = g1.w, gd = g2.x;
        const float gA = (gr - gl) * (gd - gu);
        const float lx = fmaxf(pl, gl);
        const float rx = fminf(pr, gr);
        const float uy = fmaxf(pu, gu);
        const float dy2 = fminf(pd, gd);
        const float inter = (rx - lx) * (dy2 - uy);
        const float iou = ((rx < lx) || (dy2 < uy)) ? 0.0f : inter / (pA + gA - inter);
        s_iou += objf * iou;

        s_obj += objf;

        tile = next;
    }

    // wave reduction
    #pragma unroll
    for (int off = 32; off > 0; off >>= 1) {
        s_conf  += __shfl_down(s_conf,  off);
        s_coord += __shfl_down(s_coord, off);
        s_cls   += __shfl_down(s_cls,   off);
        s_iou   += __shfl_down(s_iou,   off);
        s_obj   += __shfl_down(s_obj,   off);
    }

    const int wave = threadIdx.x >> 6;
    const int lane = threadIdx.x & 63;
    if (lane == 0) {
        red[wave][0] = s_conf;
        red[wave][1] = s_coord;
        red[wave][2] = s_cls;
        red[wave][3] = s_iou;
        red[wave][4] = s_obj;
    }
    __syncthreads();
    if (threadIdx.x == 0) {
        float t0 = 0, t1 = 0, t2 = 0, t3 = 0, t4 = 0;
        #pragma unroll
        for (int w = 0; w < 4; ++w) {
            t0 += red[w][0]; t1 += red[w][1]; t2 += red[w][2];
            t3 += red[w][3]; t4 += red[w][4];
        }
        // spread accumulation: row (blockIdx & 63), each row its own 64-B line
        float* row = ws + (size_t)(blockIdx.x & (NROWS - 1)) * ROWF;
        atomicAdd(&row[0], t0);  // conf (no_other + no_sel + conf_obj)
        atomicAdd(&row[1], t1);  // coord
        atomicAdd(&row[2], t2);  // cls
        atomicAdd(&row[3], t3);  // iou
        atomicAdd(&row[4], t4);  // obj count
    }
}

__global__ __launch_bounds__(64) void yolo_loss_finalize(
    const float* __restrict__ ws, float* __restrict__ out)
{
    const int l = threadIdx.x;   // 64 lanes, one row each
    const float* row = ws + (size_t)l * ROWF;
    float a0 = row[0], a1 = row[1], a2 = row[2], a3 = row[3], a4 = row[4];
    #pragma unroll
    for (int off = 32; off > 0; off >>= 1) {
        a0 += __shfl_down(a0, off);
        a1 += __shfl_down(a1, off);
        a2 += __shfl_down(a2, off);
        a3 += __shfl_down(a3, off);
        a4 += __shfl_down(a4, off);
    }
    if (l == 0) {
        out[0] = a0 + a1 + a2;  // loss = conf + coord + cls
        out[1] = a1;            // l_coord
        out[2] = a0;            // loss_confidence
        out[3] = a2;            // l_cls
        out[4] = a3;            // iou_sum
        out[5] = a4;            // object_num
    }
}

extern "C" void kernel_launch(void* const* d_in, const int* in_sizes, int n_in,
                              void* d_out, int out_size, void* d_ws, size_t ws_size,
                              hipStream_t stream) {
    const float4* bb4 = (const float4*)d_in[0];
    const float4* gt4 = (const float4*)d_in[1];
    const int* gs_p = (const int*)d_in[2];
    const int* im_p = (const int*)d_in[3];
    float* ws = (float*)d_ws;
    float* out = (float*)d_out;

    // zero the 4 KB accumulator region every launch (deterministic)
    hipMemsetAsync(d_ws, 0, NROWS * ROWF * sizeof(float), stream);

    yolo_loss_main<<<GRID_BLKS, 256, 0, stream>>>(bb4, gt4, gs_p, im_p, ws);
    yolo_loss_finalize<<<1, 64, 0, stream>>>(ws, out);
}